// Round 1
// baseline (1516.350 us; speedup 1.0000x reference)
//
#include <hip/hip_runtime.h>
#include <stdint.h>

#define D 64

// ---------------- CSR build ----------------

__global__ void deg_kernel(const int* __restrict__ row, int* __restrict__ deg, int e) {
    int i = blockIdx.x * blockDim.x + threadIdx.x;
    if (i < e) atomicAdd(&deg[row[i]], 1);
}

__global__ void scan_kernel(const int* __restrict__ deg, int* __restrict__ off,
                            float* __restrict__ dinv, int n) {
    __shared__ int lds[1024];
    int t = threadIdx.x;
    int chunk = (n + 1023) >> 10;
    int base = t * chunk;
    int end = base + chunk; if (end > n) end = n;
    int s = 0;
    for (int i = base; i < end; ++i) {
        int d = deg[i];
        s += d;
        dinv[i] = 1.0f / (float)(d < 1 ? 1 : d);
    }
    lds[t] = s;
    __syncthreads();
    // inclusive scan (Hillis-Steele)
    for (int d = 1; d < 1024; d <<= 1) {
        int v = (t >= d) ? lds[t - d] : 0;
        __syncthreads();
        lds[t] += v;
        __syncthreads();
    }
    int run = (t > 0) ? lds[t - 1] : 0;
    for (int i = base; i < end; ++i) {
        off[i] = run;
        run += deg[i];
    }
    if (t == 1023) off[n] = lds[1023];
}

__global__ void scatter_kernel(const int* __restrict__ row, const int* __restrict__ col,
                               const int* __restrict__ off, int* __restrict__ cursor,
                               int* __restrict__ csr, int e) {
    int i = blockIdx.x * blockDim.x + threadIdx.x;
    if (i < e) {
        int r = row[i];
        int pos = off[r] + atomicAdd(&cursor[r], 1);
        csr[pos] = col[i];
    }
}

// ---------------- fused SAGE layer: aggregate + 2 GEMV + bias + ReLU + LayerNorm ----------------
// one wave per node; lane j owns feature j

__device__ __forceinline__ float bcast_lane(float v, int k) {
    return __int_as_float(__builtin_amdgcn_readlane(__float_as_int(v), k));
}

__global__ void layer_kernel(const float* __restrict__ x,
                             const int* __restrict__ csr,
                             const int* __restrict__ off,
                             const float* __restrict__ dinv,
                             const float* __restrict__ Ws, const float* __restrict__ bs,
                             const float* __restrict__ Wn, const float* __restrict__ bn,
                             const float* __restrict__ gamma, const float* __restrict__ beta,
                             float* __restrict__ xout, int n) {
    const int lane = threadIdx.x & 63;
    const int wid = (blockIdx.x * blockDim.x + threadIdx.x) >> 6;
    const int nw = (gridDim.x * blockDim.x) >> 6;

    // weight columns in registers: wsc[k] = Ws[k][lane]
    float wsc[D], wnc[D];
#pragma unroll
    for (int k = 0; k < D; ++k) {
        wsc[k] = Ws[k * D + lane];
        wnc[k] = Wn[k * D + lane];
    }
    const float bsum = bs[lane] + bn[lane];
    const float g = gamma[lane];
    const float bt = beta[lane];

    for (int node = wid; node < n; node += nw) {
        const int s = off[node];
        const int e = off[node + 1];

        // mean aggregation: 4-way unrolled gather for load-latency overlap
        float a0 = 0.f, a1 = 0.f, a2 = 0.f, a3 = 0.f;
        int p = s;
        for (; p + 3 < e; p += 4) {
            int c0 = csr[p], c1 = csr[p + 1], c2 = csr[p + 2], c3 = csr[p + 3];
            a0 += x[(size_t)c0 * D + lane];
            a1 += x[(size_t)c1 * D + lane];
            a2 += x[(size_t)c2 * D + lane];
            a3 += x[(size_t)c3 * D + lane];
        }
        for (; p < e; ++p) a0 += x[(size_t)csr[p] * D + lane];
        float nm = ((a0 + a1) + (a2 + a3)) * dinv[node];

        float xv = x[(size_t)node * D + lane];

        // h[lane] = bsum + sum_k x[k]*Ws[k][lane] + nm[k]*Wn[k][lane]
        float h = bsum;
#pragma unroll
        for (int k = 0; k < D; ++k) {
            h = fmaf(bcast_lane(xv, k), wsc[k], h);
            h = fmaf(bcast_lane(nm, k), wnc[k], h);
        }

        // ReLU
        h = fmaxf(h, 0.0f);

        // LayerNorm over 64 lanes (biased variance, eps=1e-5)
        float s1 = h, s2 = h * h;
#pragma unroll
        for (int m = 32; m >= 1; m >>= 1) {
            s1 += __shfl_xor(s1, m);
            s2 += __shfl_xor(s2, m);
        }
        float mu = s1 * (1.0f / 64.0f);
        float var = s2 * (1.0f / 64.0f) - mu * mu;
        float r = rsqrtf(var + 1e-5f);
        xout[(size_t)node * D + lane] = (h - mu) * r * g + bt;
    }
}

// ---------------- head: relu(x@hw1+hb1) @ hw2 + hb2 ----------------
// wave per node; lanes 0..31 compute h1[j] for k=0..31, lanes 32..63 for k=32..63

__global__ void head_kernel(const float* __restrict__ x,
                            const float* __restrict__ hw1, const float* __restrict__ hb1,
                            const float* __restrict__ hw2, const float* __restrict__ hb2,
                            float* __restrict__ out, int n) {
    const int lane = threadIdx.x & 63;
    const int j = lane & 31;
    const int half = lane >> 5;
    const int wid = (blockIdx.x * blockDim.x + threadIdx.x) >> 6;
    const int nw = (gridDim.x * blockDim.x) >> 6;

    float w1c[32];
#pragma unroll
    for (int k = 0; k < 32; ++k) w1c[k] = hw1[(half * 32 + k) * 32 + j];
    const float b1 = hb1[j];
    const float w2 = hw2[j];
    const float b2 = hb2[0];

    for (int node = wid; node < n; node += nw) {
        float xv = x[(size_t)node * D + lane];
        float acc = 0.0f;
#pragma unroll
        for (int k = 0; k < 32; ++k) {
            float xk = __shfl(xv, half * 32 + k);
            acc = fmaf(xk, w1c[k], acc);
        }
        acc += __shfl_xor(acc, 32);          // combine k-halves
        float h1 = fmaxf(acc + b1, 0.0f);
        float p = h1 * w2;
#pragma unroll
        for (int m = 16; m >= 1; m >>= 1) p += __shfl_xor(p, m);
        if (lane == 0) out[node] = p + b2;
    }
}

// ---------------- launch ----------------

extern "C" void kernel_launch(void* const* d_in, const int* in_sizes, int n_in,
                              void* d_out, int out_size, void* d_ws, size_t ws_size,
                              hipStream_t stream) {
    const float* x     = (const float*)d_in[0];
    const int*   ei    = (const int*)d_in[1];
    const float* Ws    = (const float*)d_in[2];
    const float* bs    = (const float*)d_in[3];
    const float* Wn    = (const float*)d_in[4];
    const float* bn    = (const float*)d_in[5];
    const float* gamma = (const float*)d_in[6];
    const float* beta  = (const float*)d_in[7];
    const float* hw1   = (const float*)d_in[8];
    const float* hb1   = (const float*)d_in[9];
    const float* hw2   = (const float*)d_in[10];
    const float* hb2   = (const float*)d_in[11];

    const int N = in_sizes[0] / D;
    const int E = in_sizes[1] / 2;
    const int L = in_sizes[2] / (D * D);
    const int* row = ei;
    const int* col = ei + E;

    char* w = (char*)d_ws;
    int*   deg    = (int*)w;    w += (size_t)N * 4;
    int*   cursor = (int*)w;    w += (size_t)N * 4;
    int*   off    = (int*)w;    w += (size_t)(N + 1) * 4;
    float* dinv   = (float*)w;  w += (size_t)N * 4;
    int*   csr    = (int*)w;    w += (size_t)E * 4;
    w = (char*)(((uintptr_t)w + 255) & ~(uintptr_t)255);
    float* xb0    = (float*)w;  w += (size_t)N * D * 4;
    float* xb1    = (float*)w;

    // zero degree + cursor (they are contiguous)
    hipMemsetAsync(deg, 0, (size_t)N * 8, stream);

    int eb = (E + 255) / 256;
    deg_kernel<<<eb, 256, 0, stream>>>(row, deg, E);
    scan_kernel<<<1, 1024, 0, stream>>>(deg, off, dinv, N);
    scatter_kernel<<<eb, 256, 0, stream>>>(row, col, off, cursor, csr, E);

    const float* xin = x;
    float* bufs[2] = { xb0, xb1 };
    for (int l = 0; l < L; ++l) {
        float* xo = bufs[l & 1];
        layer_kernel<<<1024, 256, 0, stream>>>(xin, csr, off, dinv,
            Ws + (size_t)l * D * D, bs + (size_t)l * D,
            Wn + (size_t)l * D * D, bn + (size_t)l * D,
            gamma + (size_t)l * D, beta + (size_t)l * D,
            xo, N);
        xin = xo;
    }
    head_kernel<<<1024, 256, 0, stream>>>(xin, hw1, hb1, hw2, hb2, (float*)d_out, N);
}

// Round 2
// 838.013 us; speedup vs baseline: 1.8095x; 1.8095x over previous
//
#include <hip/hip_runtime.h>
#include <stdint.h>

#define D 64

// ---------------- CSR build ----------------

__global__ void deg_kernel(const int* __restrict__ row, int* __restrict__ deg, int e) {
    int i = blockIdx.x * blockDim.x + threadIdx.x;
    if (i < e) atomicAdd(&deg[row[i]], 1);
}

__global__ void scan_kernel(const int* __restrict__ deg, int* __restrict__ off,
                            float* __restrict__ dinv, int n) {
    __shared__ int lds[1024];
    int t = threadIdx.x;
    int chunk = (n + 1023) >> 10;
    int base = t * chunk;
    int end = base + chunk; if (end > n) end = n;
    int s = 0;
    for (int i = base; i < end; ++i) {
        int d = deg[i];
        s += d;
        dinv[i] = 1.0f / (float)(d < 1 ? 1 : d);
    }
    lds[t] = s;
    __syncthreads();
    for (int d = 1; d < 1024; d <<= 1) {
        int v = (t >= d) ? lds[t - d] : 0;
        __syncthreads();
        lds[t] += v;
        __syncthreads();
    }
    int run = (t > 0) ? lds[t - 1] : 0;
    for (int i = base; i < end; ++i) {
        off[i] = run;
        run += deg[i];
    }
    if (t == 1023) off[n] = lds[1023];
}

__global__ void scatter_kernel(const int* __restrict__ row, const int* __restrict__ col,
                               const int* __restrict__ off, int* __restrict__ cursor,
                               int* __restrict__ csr, int e) {
    int i = blockIdx.x * blockDim.x + threadIdx.x;
    if (i < e) {
        int r = row[i];
        int pos = off[r] + atomicAdd(&cursor[r], 1);
        csr[pos] = col[i];
    }
}

// ---------------- gather (mean aggregate): pure memory kernel ----------------
// wave = 64 lanes = 4 edge-slots x 16 float4-chunks -> 4 rows per load instr,
// ~16 rows in flight with pipelining. Minimal VGPR -> full occupancy.

__global__ __launch_bounds__(256, 8) void gather_kernel(
        const float* __restrict__ x, const int* __restrict__ csr,
        const int* __restrict__ off, const float* __restrict__ dinv,
        float* __restrict__ agg, int n) {
    const int lane = threadIdx.x & 63;
    const int c16 = lane & 15;          // float4 chunk within row
    const int e4 = lane >> 4;           // edge slot
    const int wid = (blockIdx.x * blockDim.x + threadIdx.x) >> 6;
    const int nw = (gridDim.x * blockDim.x) >> 6;

    for (int node = wid; node < n; node += nw) {
        const int s = off[node];
        const int e = off[node + 1];
        float4 acc = make_float4(0.f, 0.f, 0.f, 0.f);
        for (int p = s + e4; p < e; p += 4) {
            const int c = csr[p];
            const float4 v = *reinterpret_cast<const float4*>(&x[(size_t)c * D + c16 * 4]);
            acc.x += v.x; acc.y += v.y; acc.z += v.z; acc.w += v.w;
        }
        // combine the 4 edge-slot groups (lanes differ by bits 16,32)
        acc.x += __shfl_xor(acc.x, 16); acc.y += __shfl_xor(acc.y, 16);
        acc.z += __shfl_xor(acc.z, 16); acc.w += __shfl_xor(acc.w, 16);
        acc.x += __shfl_xor(acc.x, 32); acc.y += __shfl_xor(acc.y, 32);
        acc.z += __shfl_xor(acc.z, 32); acc.w += __shfl_xor(acc.w, 32);
        const float di = dinv[node];
        if (e4 == 0) {
            float4 r = make_float4(acc.x * di, acc.y * di, acc.z * di, acc.w * di);
            *reinterpret_cast<float4*>(&agg[(size_t)node * D + c16 * 4]) = r;
        }
    }
}

// ---------------- transform: h = x@Ws + agg@Wn + b, ReLU, LayerNorm ----------------
// K=128 split across the 4 waves of a block: each wave holds 32 weight rows in
// VGPRs (fits this time), partials combined via LDS. In-place xout==agg safe:
// each block reads its own rows before the barrier, writes after.

__device__ __forceinline__ float bcast_lane(float v, int k) {
    return __int_as_float(__builtin_amdgcn_readlane(__float_as_int(v), k));
}

__global__ __launch_bounds__(256) void transform_kernel(
        const float* __restrict__ x, const float* __restrict__ agg,
        const float* __restrict__ Ws, const float* __restrict__ bs,
        const float* __restrict__ Wn, const float* __restrict__ bn,
        const float* __restrict__ gamma, const float* __restrict__ beta,
        float* __restrict__ xout, int n) {
    __shared__ float hpart[4][8][D];
    const int lane = threadIdx.x & 63;
    const int w = threadIdx.x >> 6;

    const float* Wsel = (w < 2) ? Ws : Wn;
    const float* src  = (w < 2) ? x : agg;
    const int krow0 = (w & 1) * 32;

    float wreg[32];
#pragma unroll
    for (int kk = 0; kk < 32; ++kk) wreg[kk] = Wsel[(krow0 + kk) * D + lane];

    const float bias = bs[lane] + bn[lane];
    const float g = gamma[lane];
    const float bt = beta[lane];

    const int per = (n + gridDim.x - 1) / gridDim.x;
    const int n0 = blockIdx.x * per;
    const int n1 = (n0 + per < n) ? (n0 + per) : n;

    for (int base = n0; base < n1; base += 8) {
#pragma unroll
        for (int j = 0; j < 8; ++j) {
            int node = base + j;
            int nc = (node < n1) ? node : (n1 - 1);     // clamp: stays in-block
            float av = src[(size_t)nc * D + krow0 + (lane & 31)];
            float p = 0.f;
#pragma unroll
            for (int kk = 0; kk < 32; ++kk)
                p = fmaf(bcast_lane(av, kk), wreg[kk], p);
            hpart[w][j][lane] = p;
        }
        __syncthreads();
#pragma unroll
        for (int j2 = 0; j2 < 2; ++j2) {
            const int jj = w * 2 + j2;
            const int node = base + jj;
            if (node < n1) {
                float h = hpart[0][jj][lane] + hpart[1][jj][lane]
                        + hpart[2][jj][lane] + hpart[3][jj][lane] + bias;
                h = fmaxf(h, 0.0f);
                float s1 = h, s2 = h * h;
#pragma unroll
                for (int m = 32; m >= 1; m >>= 1) {
                    s1 += __shfl_xor(s1, m);
                    s2 += __shfl_xor(s2, m);
                }
                float mu = s1 * (1.0f / 64.0f);
                float var = s2 * (1.0f / 64.0f) - mu * mu;
                float r = rsqrtf(var + 1e-5f);
                xout[(size_t)node * D + lane] = (h - mu) * r * g + bt;
            }
        }
        __syncthreads();
    }
}

// ---------------- head: relu(x@hw1+hb1) @ hw2 + hb2 ----------------

__global__ __launch_bounds__(256) void head_kernel(
        const float* __restrict__ x,
        const float* __restrict__ hw1, const float* __restrict__ hb1,
        const float* __restrict__ hw2, const float* __restrict__ hb2,
        float* __restrict__ out, int n) {
    const int lane = threadIdx.x & 63;
    const int j = lane & 31;
    const int half = lane >> 5;
    const int wid = (blockIdx.x * blockDim.x + threadIdx.x) >> 6;
    const int nw = (gridDim.x * blockDim.x) >> 6;

    float w1c[32];
#pragma unroll
    for (int k = 0; k < 32; ++k) w1c[k] = hw1[(half * 32 + k) * 32 + j];
    const float b1 = hb1[j];
    const float w2 = hw2[j];
    const float b2 = hb2[0];

    for (int node = wid; node < n; node += nw) {
        float xv = x[(size_t)node * D + lane];
        float acc = 0.0f;
#pragma unroll
        for (int k = 0; k < 32; ++k) {
            float xk = __shfl(xv, half * 32 + k);
            acc = fmaf(xk, w1c[k], acc);
        }
        acc += __shfl_xor(acc, 32);
        float h1 = fmaxf(acc + b1, 0.0f);
        float p = h1 * w2;
#pragma unroll
        for (int m = 16; m >= 1; m >>= 1) p += __shfl_xor(p, m);
        if (lane == 0) out[node] = p + b2;
    }
}

// ---------------- launch ----------------

extern "C" void kernel_launch(void* const* d_in, const int* in_sizes, int n_in,
                              void* d_out, int out_size, void* d_ws, size_t ws_size,
                              hipStream_t stream) {
    const float* x     = (const float*)d_in[0];
    const int*   ei    = (const int*)d_in[1];
    const float* Ws    = (const float*)d_in[2];
    const float* bs    = (const float*)d_in[3];
    const float* Wn    = (const float*)d_in[4];
    const float* bn    = (const float*)d_in[5];
    const float* gamma = (const float*)d_in[6];
    const float* beta  = (const float*)d_in[7];
    const float* hw1   = (const float*)d_in[8];
    const float* hb1   = (const float*)d_in[9];
    const float* hw2   = (const float*)d_in[10];
    const float* hb2   = (const float*)d_in[11];

    const int N = in_sizes[0] / D;
    const int E = in_sizes[1] / 2;
    const int L = in_sizes[2] / (D * D);
    const int* row = ei;
    const int* col = ei + E;

    char* w = (char*)d_ws;
    int*   deg    = (int*)w;    w += (size_t)N * 4;
    int*   cursor = (int*)w;    w += (size_t)N * 4;
    int*   off    = (int*)w;    w += (size_t)(N + 1) * 4;
    float* dinv   = (float*)w;  w += (size_t)N * 4;
    int*   csr    = (int*)w;    w += (size_t)E * 4;
    w = (char*)(((uintptr_t)w + 255) & ~(uintptr_t)255);
    float* bufA   = (float*)w;  w += (size_t)N * D * 4;
    float* bufB   = (float*)w;

    hipMemsetAsync(deg, 0, (size_t)N * 8, stream);   // deg + cursor contiguous

    const int eb = (E + 255) / 256;
    deg_kernel<<<eb, 256, 0, stream>>>(row, deg, E);
    scan_kernel<<<1, 1024, 0, stream>>>(deg, off, dinv, N);
    scatter_kernel<<<eb, 256, 0, stream>>>(row, col, off, cursor, csr, E);

    const float* xin = x;
    for (int l = 0; l < L; ++l) {
        float* aggb = (l & 1) ? bufB : bufA;
        gather_kernel<<<2048, 256, 0, stream>>>(xin, csr, off, dinv, aggb, N);
        transform_kernel<<<2048, 256, 0, stream>>>(xin, aggb,
            Ws + (size_t)l * D * D, bs + (size_t)l * D,
            Wn + (size_t)l * D * D, bn + (size_t)l * D,
            gamma + (size_t)l * D, beta + (size_t)l * D,
            aggb, N);
        xin = aggb;
    }
    head_kernel<<<2048, 256, 0, stream>>>(xin, hw1, hb1, hw2, hb2, (float*)d_out, N);
}

// Round 3
// 649.037 us; speedup vs baseline: 2.3363x; 1.2912x over previous
//
#include <hip/hip_runtime.h>
#include <stdint.h>

#define D 64
#define SCAN_CHUNK 2048   // 256 threads * 8 elements

// ---------------- CSR build ----------------

__global__ void deg_kernel(const int* __restrict__ row, int* __restrict__ deg, int e) {
    int i = blockIdx.x * blockDim.x + threadIdx.x;
    if (i < e) atomicAdd(&deg[row[i]], 1);
}

// per-block sums of deg
__global__ __launch_bounds__(256) void blocksum_kernel(
        const int* __restrict__ deg, int* __restrict__ bsum, int n) {
    const int t = threadIdx.x;
    const int base = blockIdx.x * SCAN_CHUNK + t * 8;
    int s = 0;
#pragma unroll
    for (int j = 0; j < 8; ++j) {
        int i = base + j;
        if (i < n) s += deg[i];
    }
#pragma unroll
    for (int m = 1; m < 64; m <<= 1) s += __shfl_xor(s, m);
    __shared__ int ws[4];
    if ((t & 63) == 0) ws[t >> 6] = s;
    __syncthreads();
    if (t == 0) bsum[blockIdx.x] = ws[0] + ws[1] + ws[2] + ws[3];
}

// single-wave exclusive scan of block sums (carry loop supports any nblk)
__global__ void bscan_kernel(int* __restrict__ bsum, int nblk) {
    const int lane = threadIdx.x;   // 64 threads
    int carry = 0;
    for (int base = 0; base < nblk; base += 64) {
        int i = base + lane;
        int v = (i < nblk) ? bsum[i] : 0;
        int inc = v;
#pragma unroll
        for (int m = 1; m < 64; m <<= 1) {
            int o = __shfl_up(inc, m);
            if (lane >= m) inc += o;
        }
        if (i < nblk) bsum[i] = inc - v + carry;   // exclusive
        carry += __shfl(inc, 63);
    }
}

// off[] = bbase + in-block exclusive scan; also dinv[] and off[n]
__global__ __launch_bounds__(256) void offsets_kernel(
        const int* __restrict__ deg, const int* __restrict__ bbase,
        int* __restrict__ off, float* __restrict__ dinv, int n) {
    const int t = threadIdx.x;
    const int lane = t & 63, w = t >> 6;
    const int i0 = blockIdx.x * SCAN_CHUNK + t * 8;
    int d[8];
    int s = 0;
#pragma unroll
    for (int j = 0; j < 8; ++j) {
        int i = i0 + j;
        d[j] = (i < n) ? deg[i] : 0;
        s += d[j];
    }
    int inc = s;
#pragma unroll
    for (int m = 1; m < 64; m <<= 1) {
        int o = __shfl_up(inc, m);
        if (lane >= m) inc += o;
    }
    __shared__ int ws[4];
    if (lane == 63) ws[w] = inc;
    __syncthreads();
    int wbase = 0;
    for (int k = 0; k < w; ++k) wbase += ws[k];
    int run = bbase[blockIdx.x] + wbase + (inc - s);
#pragma unroll
    for (int j = 0; j < 8; ++j) {
        int i = i0 + j;
        if (i < n) {
            off[i] = run;
            dinv[i] = 1.0f / (float)(d[j] < 1 ? 1 : d[j]);
            run += d[j];
            if (i == n - 1) off[n] = run;
        }
    }
}

__global__ void scatter_kernel(const int* __restrict__ row, const int* __restrict__ col,
                               const int* __restrict__ off, int* __restrict__ cursor,
                               int* __restrict__ csr, int e) {
    int i = blockIdx.x * blockDim.x + threadIdx.x;
    if (i < e) {
        int r = row[i];
        int pos = off[r] + atomicAdd(&cursor[r], 1);
        csr[pos] = col[i];
    }
}

// ---------------- gather (mean aggregate): pure memory kernel ----------------

__global__ __launch_bounds__(256, 8) void gather_kernel(
        const float* __restrict__ x, const int* __restrict__ csr,
        const int* __restrict__ off, const float* __restrict__ dinv,
        float* __restrict__ agg, int n) {
    const int lane = threadIdx.x & 63;
    const int c16 = lane & 15;
    const int e4 = lane >> 4;
    const int wid = (blockIdx.x * blockDim.x + threadIdx.x) >> 6;
    const int nw = (gridDim.x * blockDim.x) >> 6;

    for (int node = wid; node < n; node += nw) {
        const int s = off[node];
        const int e = off[node + 1];
        float4 acc = make_float4(0.f, 0.f, 0.f, 0.f);
        for (int p = s + e4; p < e; p += 4) {
            const int c = csr[p];
            const float4 v = *reinterpret_cast<const float4*>(&x[(size_t)c * D + c16 * 4]);
            acc.x += v.x; acc.y += v.y; acc.z += v.z; acc.w += v.w;
        }
        acc.x += __shfl_xor(acc.x, 16); acc.y += __shfl_xor(acc.y, 16);
        acc.z += __shfl_xor(acc.z, 16); acc.w += __shfl_xor(acc.w, 16);
        acc.x += __shfl_xor(acc.x, 32); acc.y += __shfl_xor(acc.y, 32);
        acc.z += __shfl_xor(acc.z, 32); acc.w += __shfl_xor(acc.w, 32);
        const float di = dinv[node];
        if (e4 == 0) {
            float4 r = make_float4(acc.x * di, acc.y * di, acc.z * di, acc.w * di);
            *reinterpret_cast<float4*>(&agg[(size_t)node * D + c16 * 4]) = r;
        }
    }
}

// ---------------- transform: h = x@Ws + agg@Wn + b, ReLU, LayerNorm ----------------

__device__ __forceinline__ float bcast_lane(float v, int k) {
    return __int_as_float(__builtin_amdgcn_readlane(__float_as_int(v), k));
}

__global__ __launch_bounds__(256) void transform_kernel(
        const float* __restrict__ x, const float* __restrict__ agg,
        const float* __restrict__ Ws, const float* __restrict__ bs,
        const float* __restrict__ Wn, const float* __restrict__ bn,
        const float* __restrict__ gamma, const float* __restrict__ beta,
        float* __restrict__ xout, int n) {
    __shared__ float hpart[4][8][D];
    const int lane = threadIdx.x & 63;
    const int w = threadIdx.x >> 6;

    const float* Wsel = (w < 2) ? Ws : Wn;
    const float* src  = (w < 2) ? x : agg;
    const int krow0 = (w & 1) * 32;

    float wreg[32];
#pragma unroll
    for (int kk = 0; kk < 32; ++kk) wreg[kk] = Wsel[(krow0 + kk) * D + lane];

    const float bias = bs[lane] + bn[lane];
    const float g = gamma[lane];
    const float bt = beta[lane];

    const int per = (n + gridDim.x - 1) / gridDim.x;
    const int n0 = blockIdx.x * per;
    const int n1 = (n0 + per < n) ? (n0 + per) : n;

    for (int base = n0; base < n1; base += 8) {
#pragma unroll
        for (int j = 0; j < 8; ++j) {
            int node = base + j;
            int nc = (node < n1) ? node : (n1 - 1);
            float av = src[(size_t)nc * D + krow0 + (lane & 31)];
            float p = 0.f;
#pragma unroll
            for (int kk = 0; kk < 32; ++kk)
                p = fmaf(bcast_lane(av, kk), wreg[kk], p);
            hpart[w][j][lane] = p;
        }
        __syncthreads();
#pragma unroll
        for (int j2 = 0; j2 < 2; ++j2) {
            const int jj = w * 2 + j2;
            const int node = base + jj;
            if (node < n1) {
                float h = hpart[0][jj][lane] + hpart[1][jj][lane]
                        + hpart[2][jj][lane] + hpart[3][jj][lane] + bias;
                h = fmaxf(h, 0.0f);
                float s1 = h, s2 = h * h;
#pragma unroll
                for (int m = 32; m >= 1; m >>= 1) {
                    s1 += __shfl_xor(s1, m);
                    s2 += __shfl_xor(s2, m);
                }
                float mu = s1 * (1.0f / 64.0f);
                float var = s2 * (1.0f / 64.0f) - mu * mu;
                float r = rsqrtf(var + 1e-5f);
                xout[(size_t)node * D + lane] = (h - mu) * r * g + bt;
            }
        }
        __syncthreads();
    }
}

// ---------------- head ----------------

__global__ __launch_bounds__(256) void head_kernel(
        const float* __restrict__ x,
        const float* __restrict__ hw1, const float* __restrict__ hb1,
        const float* __restrict__ hw2, const float* __restrict__ hb2,
        float* __restrict__ out, int n) {
    const int lane = threadIdx.x & 63;
    const int j = lane & 31;
    const int half = lane >> 5;
    const int wid = (blockIdx.x * blockDim.x + threadIdx.x) >> 6;
    const int nw = (gridDim.x * blockDim.x) >> 6;

    float w1c[32];
#pragma unroll
    for (int k = 0; k < 32; ++k) w1c[k] = hw1[(half * 32 + k) * 32 + j];
    const float b1 = hb1[j];
    const float w2 = hw2[j];
    const float b2 = hb2[0];

    for (int node = wid; node < n; node += nw) {
        float xv = x[(size_t)node * D + lane];
        float acc = 0.0f;
#pragma unroll
        for (int k = 0; k < 32; ++k) {
            float xk = __shfl(xv, half * 32 + k);
            acc = fmaf(xk, w1c[k], acc);
        }
        acc += __shfl_xor(acc, 32);
        float h1 = fmaxf(acc + b1, 0.0f);
        float p = h1 * w2;
#pragma unroll
        for (int m = 16; m >= 1; m >>= 1) p += __shfl_xor(p, m);
        if (lane == 0) out[node] = p + b2;
    }
}

// ---------------- launch ----------------

extern "C" void kernel_launch(void* const* d_in, const int* in_sizes, int n_in,
                              void* d_out, int out_size, void* d_ws, size_t ws_size,
                              hipStream_t stream) {
    const float* x     = (const float*)d_in[0];
    const int*   ei    = (const int*)d_in[1];
    const float* Ws    = (const float*)d_in[2];
    const float* bs    = (const float*)d_in[3];
    const float* Wn    = (const float*)d_in[4];
    const float* bn    = (const float*)d_in[5];
    const float* gamma = (const float*)d_in[6];
    const float* beta  = (const float*)d_in[7];
    const float* hw1   = (const float*)d_in[8];
    const float* hb1   = (const float*)d_in[9];
    const float* hw2   = (const float*)d_in[10];
    const float* hb2   = (const float*)d_in[11];

    const int N = in_sizes[0] / D;
    const int E = in_sizes[1] / 2;
    const int L = in_sizes[2] / (D * D);
    const int* row = ei;
    const int* col = ei + E;

    const int nblk = (N + SCAN_CHUNK - 1) / SCAN_CHUNK;

    char* w = (char*)d_ws;
    int*   deg    = (int*)w;    w += (size_t)N * 4;
    int*   cursor = (int*)w;    w += (size_t)N * 4;
    int*   off    = (int*)w;    w += (size_t)(N + 1) * 4;
    float* dinv   = (float*)w;  w += (size_t)N * 4;
    int*   bsum   = (int*)w;    w += (size_t)nblk * 4;
    w = (char*)(((uintptr_t)w + 255) & ~(uintptr_t)255);
    int*   csr    = (int*)w;    w += (size_t)E * 4;
    float* bufA   = (float*)w;  w += (size_t)N * D * 4;
    float* bufB   = (float*)w;

    hipMemsetAsync(deg, 0, (size_t)N * 8, stream);   // deg + cursor contiguous

    const int eb = (E + 255) / 256;
    deg_kernel<<<eb, 256, 0, stream>>>(row, deg, E);
    blocksum_kernel<<<nblk, 256, 0, stream>>>(deg, bsum, N);
    bscan_kernel<<<1, 64, 0, stream>>>(bsum, nblk);
    offsets_kernel<<<nblk, 256, 0, stream>>>(deg, bsum, off, dinv, N);
    scatter_kernel<<<eb, 256, 0, stream>>>(row, col, off, cursor, csr, E);

    const float* xin = x;
    for (int l = 0; l < L; ++l) {
        float* aggb = (l & 1) ? bufB : bufA;
        gather_kernel<<<2048, 256, 0, stream>>>(xin, csr, off, dinv, aggb, N);
        transform_kernel<<<2048, 256, 0, stream>>>(xin, aggb,
            Ws + (size_t)l * D * D, bs + (size_t)l * D,
            Wn + (size_t)l * D * D, bn + (size_t)l * D,
            gamma + (size_t)l * D, beta + (size_t)l * D,
            aggb, N);
        xin = aggb;
    }
    head_kernel<<<2048, 256, 0, stream>>>(xin, hw1, hb1, hw2, hb2, (float*)d_out, N);
}